// Round 4
// baseline (1344.662 us; speedup 1.0000x reference)
//
#include <hip/hip_runtime.h>
#include <stdint.h>

// ---------- types ----------
typedef _Float16 f16;
typedef _Float16 f16x8 __attribute__((ext_vector_type(8)));
typedef _Float16 f16x4 __attribute__((ext_vector_type(4)));
typedef float    f32x4 __attribute__((ext_vector_type(4)));

#define B_DIM 2048
#define N_DIM 65536
#define H_DIM 1024

typedef const __attribute__((address_space(1))) void g_void;
typedef __attribute__((address_space(3))) void l_void;
__device__ __forceinline__ void glds16(const void* g, void* l) {
    __builtin_amdgcn_global_load_lds((g_void*)g, (l_void*)l, 16, 0, 0);
}

// ---------- small prep kernels ----------
__global__ __launch_bounds__(256) void k_weights(const float* __restrict__ imp,
                                                 const float* __restrict__ ts,
                                                 float* __restrict__ w,
                                                 float* __restrict__ sumw) {
    int i = blockIdx.x * 256 + threadIdx.x;
    float age = 1.0f - ts[i];
    float r = expf(-fabsf(age) * (float)(1.0 - 0.99));
    float wv = r * (imp[i] + 1.0f);
    w[i] = wv;
    for (int off = 32; off; off >>= 1) wv += __shfl_down(wv, off, 64);
    __shared__ float ps[4];
    if ((threadIdx.x & 63) == 0) ps[threadIdx.x >> 6] = wv;
    __syncthreads();
    if (threadIdx.x == 0) atomicAdd(sumw, ps[0] + ps[1] + ps[2] + ps[3]);
}

// split fp32 -> fp16 hi + fp16 lo (8 floats/thread, 16B stores)
__global__ __launch_bounds__(256) void k_split(const float* __restrict__ x,
                                               f16* __restrict__ hi, f16* __restrict__ lo) {
    size_t i = (size_t)blockIdx.x * 256 + threadIdx.x;
    float4 v0 = ((const float4*)x)[2 * i];
    float4 v1 = ((const float4*)x)[2 * i + 1];
    float vv[8] = {v0.x, v0.y, v0.z, v0.w, v1.x, v1.y, v1.z, v1.w};
    f16x8 h, l;
#pragma unroll
    for (int j = 0; j < 8; j++) { h[j] = (f16)vv[j]; l[j] = (f16)(vv[j] - (float)h[j]); }
    ((f16x8*)hi)[i] = h;
    ((f16x8*)lo)[i] = l;
}

__global__ __launch_bounds__(256) void k_tohalf(const float* __restrict__ x, f16* __restrict__ h) {
    size_t i = (size_t)blockIdx.x * 256 + threadIdx.x;
    float4 v0 = ((const float4*)x)[2 * i];
    float4 v1 = ((const float4*)x)[2 * i + 1];
    f16x8 o = {(f16)v0.x, (f16)v0.y, (f16)v0.z, (f16)v0.w,
               (f16)v1.x, (f16)v1.y, (f16)v1.z, (f16)v1.w};
    ((f16x8*)h)[i] = o;
}

// transpose-split: wkT[j,k] = Wk[k,j] -> f16 hi + lo
__global__ __launch_bounds__(256) void k_tsplit(const float* __restrict__ Wm,
                                                f16* __restrict__ th, f16* __restrict__ tl_) {
    __shared__ float tl[64][65];
    const int t = threadIdx.x;
    const int r0 = blockIdx.y * 64, c0 = blockIdx.x * 64;
#pragma unroll
    for (int p = 0; p < 16; ++p) {
        int idx = p * 256 + t;
        int r = idx >> 6, c = idx & 63;
        tl[r][c] = Wm[(size_t)(r0 + r) * H_DIM + c0 + c];
    }
    __syncthreads();
#pragma unroll
    for (int p = 0; p < 16; ++p) {
        int idx = p * 256 + t;
        int oc = idx >> 6, rr = idx & 63;
        float v = tl[rr][oc];
        f16 h = (f16)v;
        th[(size_t)(c0 + oc) * H_DIM + r0 + rr] = h;
        tl_[(size_t)(c0 + oc) * H_DIM + r0 + rr] = (f16)(v - (float)h);
    }
}

// q row-normalize -> fp16 hi + lo
__global__ __launch_bounds__(256) void k_qnorm(const float* __restrict__ q,
                                               f16* __restrict__ qh, f16* __restrict__ ql) {
    int b = blockIdx.x, t = threadIdx.x;
    float4 v = ((const float4*)(q + (size_t)b * H_DIM))[t];
    float ss = v.x * v.x + v.y * v.y + v.z * v.z + v.w * v.w;
    for (int off = 32; off; off >>= 1) ss += __shfl_down(ss, off, 64);
    __shared__ float ps[4];
    if ((t & 63) == 0) ps[t >> 6] = ss;
    __syncthreads();
    float tot = ps[0] + ps[1] + ps[2] + ps[3];
    float rn = 1.0f / fmaxf(sqrtf(tot), 1e-12f);
    float o[4] = {v.x * rn, v.y * rn, v.z * rn, v.w * rn};
    f16x4 h, l;
#pragma unroll
    for (int j = 0; j < 4; j++) { h[j] = (f16)o[j]; l[j] = (f16)(o[j] - (float)h[j]); }
    ((f16x4*)(qh + (size_t)b * H_DIM))[t] = h;
    ((f16x4*)(ql + (size_t)b * H_DIM))[t] = l;
}

// finalize sscale[n] = w[n] / ((sumw+1e-8) * max(sqrt(nrm2[n]),1e-12))
__global__ __launch_bounds__(256) void k_fin(const float* __restrict__ w,
                                             const float* __restrict__ sumw,
                                             const float* __restrict__ nrm2,
                                             float* __restrict__ sscale) {
    int i = blockIdx.x * 256 + threadIdx.x;
    sscale[i] = w[i] / ((sumw[0] + 1e-8f) * fmaxf(sqrtf(nrm2[i]), 1e-12f));
}

// ---------- 8-phase 256x256 GEMM, BK=64, 512 thr (8 waves 2Mx4N), 16x16x32 f16 MFMA ----------
// OUTMODE 0: norm GEMM  C = (storeHi+storeLo) @ (wkHi+wkLo).T (3-term split, virtual K=3072);
//            no C write; epilogue atomicAdd row-wise sum(C^2) -> nrm2
// OUTMODE 1: sim GEMM   C = qk16 @ storeHi.T (K=1024); epilogue: v*colscale, per-row top-8
//            over this block's 256 cols -> packed u32 (mono24|col8) -> cand buffer
//
// LDS (128 KiB): A: 2 bufs x [256 rows][64 f16] at 0/32768; B: same at 65536/98304.
//   B rows permuted: lds rows 0-127 = "even" 32-col halves, rows 128-255 = "odd" halves.
//   XOR swizzle: byte slot ^= (lds_row&7)<<4; staged via inverse-swizzled global source.
// Pipeline: tile t+1 staged in 2 groups of 4 glds16; waits vmcnt(4) at phases 0,3 (each
//   retires one 4-load group; loads stay in flight across barriers, never drained).

#define RD_A(AB, H)                                                              \
    _Pragma("unroll") for (int mi = 0; mi < 4; ++mi) {                           \
        a[mi][0] = *(const f16x8*)(lds + (AB) + arow + (H)*8192 + mi*2048 + acol0); \
        a[mi][1] = *(const f16x8*)(lds + (AB) + arow + (H)*8192 + mi*2048 + acol1); \
    }

#define RD_B(DST, BB, OFFH)                                                      \
    _Pragma("unroll") for (int nj = 0; nj < 2; ++nj) {                           \
        DST[nj][0] = *(const f16x8*)(lds + (BB) + (OFFH) + brow + nj*2048 + acol0); \
        DST[nj][1] = *(const f16x8*)(lds + (BB) + (OFFH) + brow + nj*2048 + acol1); \
    }

#define PH_PRE()                                                                 \
    __builtin_amdgcn_s_barrier();                                                \
    asm volatile("s_waitcnt lgkmcnt(0)" ::: "memory");                           \
    __builtin_amdgcn_sched_barrier(0);                                           \
    __builtin_amdgcn_s_setprio(1);

#define PH_POST()                                                                \
    __builtin_amdgcn_s_setprio(0);                                               \
    __builtin_amdgcn_s_barrier();

#define MFMA8x2(MH, BV, NB)                                                      \
    _Pragma("unroll") for (int ks = 0; ks < 2; ++ks)                             \
    _Pragma("unroll") for (int mi = 0; mi < 4; ++mi)                             \
    _Pragma("unroll") for (int nj = 0; nj < 2; ++nj)                             \
        acc[(MH)*4 + mi][(NB) + nj] = __builtin_amdgcn_mfma_f32_16x16x32_f16(    \
            a[mi][ks], BV[nj][ks], acc[(MH)*4 + mi][(NB) + nj], 0, 0, 0);

#define TILE_BODY(T, STG, W0STR)                                                 \
  {                                                                              \
    const int cur = (T) & 1;                                                     \
    const int ab = cur * 32768;                                                  \
    const int bb = 65536 + cur * 32768;                                          \
    const int da = (cur ^ 1) * 32768;                                            \
    const int db = 65536 + (cur ^ 1) * 32768;                                    \
    const f16* An = A0; const f16* Bn = Bh; int toffn = 0;                       \
    if (STG) {                                                                   \
        const int tn = (T) + 1;                                                  \
        if constexpr (OUTMODE == 0) {                                            \
            An = (tn < 16) ? A0 : (tn < 32 ? A1 : A0);                           \
            Bn = (tn < 32) ? Bh : Bl;                                            \
            toffn = (tn & 15) * 64;                                              \
        } else { toffn = tn * 64; }                                              \
    }                                                                            \
    /* phase 0: (m-lo, n-even) */                                                \
    RD_A(ab, 0)                                                                  \
    RD_B(b0, bb, 0)                                                              \
    if (STG) {                                                                   \
        glds16(An + aoff0 + toffn, lds + da + tid * 16);                         \
        glds16(An + aoff2 + toffn, lds + da + 16384 + tid * 16);                 \
        glds16(Bn + boffE1 + toffn, lds + db + tid * 16);                        \
        glds16(Bn + boffE2 + toffn, lds + db + 8192 + tid * 16);                 \
    }                                                                            \
    asm volatile("s_waitcnt vmcnt(" W0STR ")" ::: "memory");                     \
    PH_PRE() MFMA8x2(0, b0, 0) PH_POST()                                         \
    /* phase 1: (m-lo, n-odd) */                                                 \
    RD_B(b1, bb, 16384)                                                          \
    if (STG) {                                                                   \
        glds16(Bn + boffO1 + toffn, lds + db + 16384 + tid * 16);                \
        glds16(Bn + boffO2 + toffn, lds + db + 24576 + tid * 16);                \
        glds16(An + aoff1 + toffn, lds + da + 8192 + tid * 16);                  \
        glds16(An + aoff3 + toffn, lds + da + 24576 + tid * 16);                 \
    }                                                                            \
    PH_PRE() MFMA8x2(0, b1, 2) PH_POST()                                         \
    /* phase 2: (m-hi, n-odd) */                                                 \
    RD_A(ab, 1)                                                                  \
    PH_PRE() MFMA8x2(1, b1, 2) PH_POST()                                         \
    /* phase 3: (m-hi, n-even) */                                                \
    asm volatile("s_waitcnt vmcnt(4)" ::: "memory");                             \
    PH_PRE() MFMA8x2(1, b0, 0) PH_POST()                                         \
  }

template <int OUTMODE>
__global__ __launch_bounds__(512) void k_gemm8(
    const f16* __restrict__ A0, const f16* __restrict__ A1,
    const f16* __restrict__ Bh, const f16* __restrict__ Bl,
    unsigned int* __restrict__ cand, const float* __restrict__ colscale,
    float* __restrict__ nrm2) {
    __shared__ char lds[131072];
    const int tid = threadIdx.x;

    constexpr int NT = (OUTMODE == 0) ? 48 : 16;  // virtual K = 3072 (split) vs 1024

    // XCD-chunked bijective block swizzle
    int m0, n0;
    {
        const int f = blockIdx.x;
        if constexpr (OUTMODE == 0) {
            // 1024 blocks = 256 M-tiles x 4 N-tiles, N fastest within an XCD chunk of 128
            const int lg = (f & 7) * 128 + (f >> 3);
            m0 = (lg >> 2) * 256; n0 = (lg & 3) * 256;
        } else {
            // 2048 blocks = 8 M-tiles x 256 N-tiles, M fastest within an XCD chunk of 256
            const int lg = (f & 7) * 256 + (f >> 3);
            m0 = (lg & 7) * 256; n0 = (lg >> 3) * 256;
        }
    }

    // staging coords: thread -> (row-in-chunk, 16B slot); global source pre-inverse-swizzled
    const int sr = tid >> 3, ss = tid & 7;
    const int ssw = (ss ^ (sr & 7)) * 8;  // element offset
    const size_t aoff0 = (size_t)(m0 + sr) * H_DIM + ssw;
    const size_t aoff1 = (size_t)(m0 + 64 + sr) * H_DIM + ssw;
    const size_t aoff2 = (size_t)(m0 + 128 + sr) * H_DIM + ssw;
    const size_t aoff3 = (size_t)(m0 + 192 + sr) * H_DIM + ssw;
    const int nE = (sr >> 5) * 64 + (sr & 31);
    const size_t boffE1 = (size_t)(n0 + nE) * H_DIM + ssw;
    const size_t boffE2 = (size_t)(n0 + nE + 128) * H_DIM + ssw;
    const size_t boffO1 = (size_t)(n0 + nE + 32) * H_DIM + ssw;
    const size_t boffO2 = (size_t)(n0 + nE + 160) * H_DIM + ssw;

    // reader coords
    const int lane = tid & 63, wave = tid >> 6;
    const int wr = wave >> 2, wc = wave & 3;
    const int m16 = lane & 15, q4 = lane >> 4;
    const int axor = (lane & 7) << 4;
    const int acol0 = (q4 * 16) ^ axor;
    const int acol1 = (64 + q4 * 16) ^ axor;
    const int arow = (wr * 128 + m16) * 128;
    const int brow = (wc * 32 + m16) * 128;

    f32x4 acc[8][4];
#pragma unroll
    for (int i = 0; i < 8; i++)
#pragma unroll
        for (int j = 0; j < 4; j++) acc[i][j] = (f32x4){0.f, 0.f, 0.f, 0.f};
    f16x8 a[4][2], b0[2][2], b1[2][2];

    // prologue: stage tile 0 into buf0 (group1 then group2), wait group1, barrier
    glds16(A0 + aoff0, lds + tid * 16);
    glds16(A0 + aoff2, lds + 16384 + tid * 16);
    glds16(Bh + boffE1, lds + 65536 + tid * 16);
    glds16(Bh + boffE2, lds + 65536 + 8192 + tid * 16);
    glds16(Bh + boffO1, lds + 65536 + 16384 + tid * 16);
    glds16(Bh + boffO2, lds + 65536 + 24576 + tid * 16);
    glds16(A0 + aoff1, lds + 8192 + tid * 16);
    glds16(A0 + aoff3, lds + 24576 + tid * 16);
    asm volatile("s_waitcnt vmcnt(4)" ::: "memory");
    __builtin_amdgcn_s_barrier();

    for (int t = 0; t < NT - 1; ++t) TILE_BODY(t, 1, "4")
    TILE_BODY(NT - 1, 0, "0")

    if constexpr (OUTMODE == 0) {
        // row-wise sum of squares over this block's 256 cols -> atomicAdd into nrm2
#pragma unroll
        for (int mi = 0; mi < 8; ++mi)
#pragma unroll
            for (int rr = 0; rr < 4; ++rr) {
                float s = 0.f;
#pragma unroll
                for (int njj = 0; njj < 4; ++njj) {
                    float v = acc[mi][njj][rr];
                    s += v * v;
                }
                s += __shfl_xor(s, 1, 64);
                s += __shfl_xor(s, 2, 64);
                s += __shfl_xor(s, 4, 64);
                s += __shfl_xor(s, 8, 64);
                if (m16 == 0)
                    atomicAdd(&nrm2[m0 + wr * 128 + mi * 16 + q4 * 4 + rr], s);
            }
    } else {
        // fused per-row top-8 over this block's 256 cols
        float cs0 = colscale[n0 + wc * 64 + m16];
        float cs1 = colscale[n0 + wc * 64 + 16 + m16];
        float cs2 = colscale[n0 + wc * 64 + 32 + m16];
        float cs3 = colscale[n0 + wc * 64 + 48 + m16];
#pragma unroll
        for (int mi = 0; mi < 8; ++mi)
#pragma unroll
            for (int njj = 0; njj < 4; ++njj) {
                const float c = (njj == 0) ? cs0 : (njj == 1) ? cs1 : (njj == 2) ? cs2 : cs3;
#pragma unroll
                for (int rr = 0; rr < 4; ++rr) acc[mi][njj][rr] *= c;
            }

        float* ldsf = (float*)lds;
        const int r = tid >> 2;        // row within half (0..127)
        const int seg = tid & 3;       // 64-col segment
        const int g5 = tid & 31;       // bank-spread XOR for scan order
        const int chunkbase = (n0 >> 8) * 8;

#pragma unroll 1
        for (int half = 0; half < 2; ++half) {
            __syncthreads();
            if (wr == half) {
#pragma unroll
                for (int mi = 0; mi < 8; ++mi)
#pragma unroll
                    for (int njj = 0; njj < 4; ++njj)
#pragma unroll
                        for (int rr = 0; rr < 4; ++rr) {
                            int row = mi * 16 + q4 * 4 + rr;
                            int col = wc * 64 + (njj >> 1) * 32 + (njj & 1) * 16 + m16;
                            ldsf[row * 256 + col] = acc[mi][njj][rr];
                        }
            }
            __syncthreads();

            unsigned int tk[8];
#pragma unroll
            for (int i = 0; i < 8; ++i) tk[i] = 0u;
            unsigned int mn = 0u; int mslot = 0;
            for (int jj = 0; jj < 64; ++jj) {
                const int pos = seg * 64 + (jj ^ g5);   // g5<32 keeps pos in segment
                float v = ldsf[r * 256 + pos];
                unsigned int u = __builtin_bit_cast(unsigned int, v);
                u = (u & 0x80000000u) ? ~u : (u | 0x80000000u);
                unsigned int key = (u & 0xFFFFFF00u) | (unsigned)pos;
                if (key > mn) {
#pragma unroll
                    for (int i = 0; i < 8; ++i) tk[i] = (i == mslot) ? key : tk[i];
                    mn = tk[0]; mslot = 0;
#pragma unroll
                    for (int i = 1; i < 8; ++i) { if (tk[i] < mn) { mn = tk[i]; mslot = i; } }
                }
            }
            // merge 4 lanes (same row) -> top-8
            unsigned int win0, win1, win2, win3, win4, win5, win6, win7;
#pragma unroll
            for (int e = 0; e < 8; ++e) {
                unsigned int lm = tk[0];
#pragma unroll
                for (int i = 1; i < 8; ++i) lm = max(lm, tk[i]);
                unsigned int o1 = max(lm, __shfl_xor(lm, 1, 64));
                unsigned int o2 = max(o1, __shfl_xor(o1, 2, 64));
                if (e == 0) win0 = o2; else if (e == 1) win1 = o2; else if (e == 2) win2 = o2;
                else if (e == 3) win3 = o2; else if (e == 4) win4 = o2; else if (e == 5) win5 = o2;
                else if (e == 6) win6 = o2; else win7 = o2;
#pragma unroll
                for (int i = 0; i < 8; ++i) tk[i] = (tk[i] == o2) ? 0u : tk[i];
            }
            if (seg == 0) {
                const int b = m0 + half * 128 + r;
                uint4* dst = (uint4*)(cand + (size_t)b * 2048 + chunkbase);
                dst[0] = (uint4){win0, win1, win2, win3};
                dst[1] = (uint4){win4, win5, win6, win7};
            }
        }
    }
    (void)A1; (void)Bl; (void)nrm2; (void)colscale; (void)cand;
}

// ---------- small GEMM: C[2048,1024] = A[2048,1024] * B[1024,1024]^T ; 64x128 tile ----------
// OUTMODE 2: fp16 out; OUTMODE 3: fp32 out; OUTMODE 4: 3-term fp16-split (A=Ah+Al, B=Bh+Bl), fp32+fp16 out
template <int OUTMODE>
__global__ __launch_bounds__(256) void k_gemm64(const f16* __restrict__ A, const f16* __restrict__ Al,
                                                const f16* __restrict__ B, const f16* __restrict__ Bl,
                                                float* __restrict__ of32, f16* __restrict__ of16) {
    __shared__ f16 As[64 * 32];
    __shared__ f16 Bs[128 * 32];
    __shared__ f16 AsL[(OUTMODE == 4) ? 64 * 32 : 1];
    __shared__ f16 BsL[(OUTMODE == 4) ? 128 * 32 : 1];
    const int tid = threadIdx.x;
    const int m0 = blockIdx.y * 64, n0 = blockIdx.x * 128;
    const int r = tid >> 2, c8 = (tid & 3) * 8;
    const f16* ga = A + (size_t)(m0 + r) * H_DIM + c8;
    const f16* gb0 = B + (size_t)(n0 + r) * H_DIM + c8;
    const f16* gb1 = B + (size_t)(n0 + r + 64) * H_DIM + c8;
    const f16 *gal = nullptr, *gbl0 = nullptr, *gbl1 = nullptr;
    if constexpr (OUTMODE == 4) {
        gal = Al + (size_t)(m0 + r) * H_DIM + c8;
        gbl0 = Bl + (size_t)(n0 + r) * H_DIM + c8;
        gbl1 = Bl + (size_t)(n0 + r + 64) * H_DIM + c8;
    }

    const int lane = tid & 63, wave = tid >> 6;
    const int wn = wave * 32;
    const int q4 = lane >> 4, m16 = lane & 15;
    const int aoff = m16 * 32 + q4 * 8;
    const int boff = (wn + m16) * 32 + q4 * 8;

    f32x4 acc[4][2];
#pragma unroll
    for (int i = 0; i < 4; i++)
#pragma unroll
        for (int j = 0; j < 2; j++) acc[i][j] = (f32x4){0.f, 0.f, 0.f, 0.f};

    for (int k0 = 0; k0 < H_DIM; k0 += 32) {
        __syncthreads();
        glds16(ga + k0, As + tid * 8);
        glds16(gb0 + k0, Bs + tid * 8);
        glds16(gb1 + k0, Bs + 2048 + tid * 8);
        if constexpr (OUTMODE == 4) {
            glds16(gal + k0, AsL + tid * 8);
            glds16(gbl0 + k0, BsL + tid * 8);
            glds16(gbl1 + k0, BsL + 2048 + tid * 8);
        }
        __syncthreads();
        f16x8 a[4], b[2], al[4], bl[2];
#pragma unroll
        for (int i = 0; i < 4; i++) a[i] = *(const f16x8*)(As + aoff + i * 512);
#pragma unroll
        for (int j = 0; j < 2; j++) b[j] = *(const f16x8*)(Bs + boff + j * 512);
        if constexpr (OUTMODE == 4) {
#pragma unroll
            for (int i = 0; i < 4; i++) al[i] = *(const f16x8*)(AsL + aoff + i * 512);
#pragma unroll
            for (int j = 0; j < 2; j++) bl[j] = *(const f16x8*)(BsL + boff + j * 512);
        }
#pragma unroll
        for (int i = 0; i < 4; i++)
#pragma unroll
            for (int j = 0; j < 2; j++) {
                if constexpr (OUTMODE == 4) {
                    acc[i][j] = __builtin_amdgcn_mfma_f32_16x16x32_f16(al[i], b[j], acc[i][j], 0, 0, 0);
                    acc[i][j] = __builtin_amdgcn_mfma_f32_16x16x32_f16(a[i], bl[j], acc[i][j], 0, 0, 0);
                }
                acc[i][j] = __builtin_amdgcn_mfma_f32_16x16x32_f16(a[i], b[j], acc[i][j], 0, 0, 0);
            }
    }

#pragma unroll
    for (int i = 0; i < 4; i++) {
        const int rowb = m0 + i * 16 + q4 * 4;
#pragma unroll
        for (int j = 0; j < 2; j++) {
            const int col = n0 + wn + j * 16 + m16;
#pragma unroll
            for (int rr = 0; rr < 4; rr++) {
                const float v = acc[i][j][rr];
                const size_t o = (size_t)(rowb + rr) * H_DIM + col;
                if constexpr (OUTMODE == 2) of16[o] = (f16)v;
                else if constexpr (OUTMODE == 3) of32[o] = v;
                else { of32[o] = v; of16[o] = (f16)v; }
            }
        }
    }
}

// ---------- merge 2048 packed cands -> top-16; fp32 rescore; top-8 + softmax; combine ----------
__global__ __launch_bounds__(256) void k_merge2(const unsigned int* __restrict__ cand,
                                                const float* __restrict__ qk32,
                                                const float* __restrict__ sscale,
                                                const float* __restrict__ store,
                                                f16* __restrict__ s16) {
    const int b = blockIdx.x, t = threadIdx.x;
    __shared__ unsigned int cl[2048];
    __shared__ unsigned int wmax[2][4];
    __shared__ int c16[16];
    __shared__ float rs[16];
    __shared__ float a8[8];
    __shared__ int i8[8];

    uint4 e0 = ((const uint4*)(cand + (size_t)b * 2048))[t * 2];
    uint4 e1 = ((const uint4*)(cand + (size_t)b * 2048))[t * 2 + 1];
    ((uint4*)cl)[t * 2] = e0;
    ((uint4*)cl)[t * 2 + 1] = e1;
    unsigned int k_[8] = {e0.x, e0.y, e0.z, e0.w, e1.x, e1.y, e1.z, e1.w};
#pragma unroll
    for (int i = 0; i < 8; ++i) k_[i] = (k_[i] & 0xFFFFF800u) | (unsigned)(t * 8 + i);
    __syncthreads();

    const int w = t >> 6;
    for (int rnd = 0; rnd < 16; ++rnd) {
        unsigned int lm = k_[0];
#pragma unroll
        for (int i = 1; i < 8; ++i) lm = max(lm, k_[i]);
        for (int off = 32; off; off >>= 1) lm = max(lm, __shfl_down(lm, off, 64));
        if ((t & 63) == 0) wmax[rnd & 1][w] = lm;
        __syncthreads();
        unsigned int win = max(max(wmax[rnd & 1][0], wmax[rnd & 1][1]),
                               max(wmax[rnd & 1][2], wmax[rnd & 1][3]));
        int idx = (int)(win & 0x7FFu);
        if (t == 0) c16[rnd] = (idx >> 3) * 256 + (int)(cl[idx] & 0xFFu);
        const bool own = (idx >> 3) == t;
#pragma unroll
        for (int i = 0; i < 8; ++i) k_[i] = (own && i == (idx & 7)) ? 0u : k_[i];
    }
    __syncthreads();

    // fp32 rescore: group g (16 lanes) handles candidate g; score = qk32[b] . store[idx] * sscale[idx]
    const int g = t >> 4, l16 = t & 15;
    const int idx = c16[g];
    const float* kr = store + (size_t)idx * H_DIM;
    const float* qr = qk32 + (size_t)b * H_DIM;
    float sum = 0.f;
#pragma unroll 8
    for (int j = 0; j < 64; j++) {
        int k = l16 + j * 16;
        sum += qr[k] * kr[k];
    }
    for (int off = 8; off; off >>= 1) sum += __shfl_down(sum, off, 16);
    if (l16 == 0) rs[g] = sum * sscale[idx];
    __syncthreads();

    if (t == 0) {
        float v[16];
        for (int i = 0; i < 16; i++) v[i] = rs[i];
        float av[8]; int ai[8];
        for (int it = 0; it < 8; ++it) {
            float bm = -1e30f; int mi = 0;
            for (int i = 0; i < 16; i++)
                if (v[i] > bm) { bm = v[i]; mi = i; }
            av[it] = bm; ai[it] = c16[mi]; v[mi] = -1e30f;
        }
        float m = av[0], e[8], ssum = 0.f;
        for (int k = 0; k < 8; k++) { e[k] = expf(av[k] - m); ssum += e[k]; }
        for (int k = 0; k < 8; k++) { a8[k] = e[k] / ssum; i8[k] = ai[k]; }
    }
    __syncthreads();

#pragma unroll
    for (int p = 0; p < 4; p++) {
        const int col = t + p * 256;
        float sum2 = 0.f;
#pragma unroll
        for (int k = 0; k < 8; k++) sum2 += a8[k] * store[(size_t)i8[k] * H_DIM + col];
        s16[(size_t)b * H_DIM + col] = (f16)sum2;
    }
}

// ---------- workspace layout (bytes) ----------
#define MB (1024ull * 1024ull)
#define OFF_STOREHI (0ull)               // 128 MB
#define OFF_STORELO (128ull * MB)        // 128 MB
#define OFF_CAND    (256ull * MB)        // 16 MB (packed top-8 per (query, 256-col chunk))
#define OFF_WKHI    (512ull * MB)        // 2 MB
#define OFF_WKLO    (514ull * MB)        // 2 MB
#define OFF_WKTH    (516ull * MB)        // 2 MB
#define OFF_WKTL    (518ull * MB)        // 2 MB
#define OFF_QNHI    (520ull * MB)        // 4 MB
#define OFF_QNLO    (524ull * MB)        // 4 MB
#define OFF_QK32    (528ull * MB)        // 8 MB
#define OFF_QK16    (536ull * MB)        // 4 MB
#define OFF_WV16    (540ull * MB)        // 2 MB
#define OFF_WO16    (542ull * MB)        // 2 MB
#define OFF_W       (544ull * MB)        // 256 KB
#define OFF_SSCALE  (544ull * MB + 256ull * 1024ull)
#define OFF_SUMW    (544ull * MB + 512ull * 1024ull)
#define OFF_NRM2    (544ull * MB + 768ull * 1024ull)  // 256 KB
#define OFF_S16     (546ull * MB)        // 4 MB
#define OFF_T16     (550ull * MB)        // 4 MB

extern "C" void kernel_launch(void* const* d_in, const int* in_sizes, int n_in,
                              void* d_out, int out_size, void* d_ws, size_t ws_size,
                              hipStream_t stream) {
    const float* q     = (const float*)d_in[0];
    const float* store = (const float*)d_in[1];
    const float* imp   = (const float*)d_in[2];
    const float* ts    = (const float*)d_in[3];
    const float* Wk    = (const float*)d_in[4];
    const float* Wv    = (const float*)d_in[5];
    const float* Wo    = (const float*)d_in[6];
    float* out = (float*)d_out;
    char* ws = (char*)d_ws;

    f16* storeHi = (f16*)(ws + OFF_STOREHI);
    f16* storeLo = (f16*)(ws + OFF_STORELO);
    unsigned int* cand = (unsigned int*)(ws + OFF_CAND);
    f16* wkHi = (f16*)(ws + OFF_WKHI);
    f16* wkLo = (f16*)(ws + OFF_WKLO);
    f16* wkTh = (f16*)(ws + OFF_WKTH);
    f16* wkTl = (f16*)(ws + OFF_WKTL);
    f16* qnHi = (f16*)(ws + OFF_QNHI);
    f16* qnLo = (f16*)(ws + OFF_QNLO);
    float* qk32 = (float*)(ws + OFF_QK32);
    f16* qk16 = (f16*)(ws + OFF_QK16);
    f16* wv16 = (f16*)(ws + OFF_WV16);
    f16* wo16 = (f16*)(ws + OFF_WO16);
    float* wbuf = (float*)(ws + OFF_W);
    float* sscale = (float*)(ws + OFF_SSCALE);
    float* sumw = (float*)(ws + OFF_SUMW);
    float* nrm2 = (float*)(ws + OFF_NRM2);
    f16* s16 = (f16*)(ws + OFF_S16);
    f16* t16 = (f16*)(ws + OFF_T16);

    hipMemsetAsync(sumw, 0, 4, stream);
    hipMemsetAsync(nrm2, 0, N_DIM * 4, stream);

    // prep
    k_weights<<<N_DIM / 256, 256, 0, stream>>>(imp, ts, wbuf, sumw);
    k_split<<<(N_DIM * H_DIM) / 2048, 256, 0, stream>>>(store, storeHi, storeLo);
    k_split<<<(H_DIM * H_DIM) / 2048, 256, 0, stream>>>(Wk, wkHi, wkLo);
    k_tsplit<<<dim3(16, 16), 256, 0, stream>>>(Wk, wkTh, wkTl);
    k_tohalf<<<(H_DIM * H_DIM) / 2048, 256, 0, stream>>>(Wv, wv16);
    k_tohalf<<<(H_DIM * H_DIM) / 2048, 256, 0, stream>>>(Wo, wo16);
    k_qnorm<<<B_DIM, 256, 0, stream>>>(q, qnHi, qnLo);

    // qk = qn @ Wk (3-term fp16 split -> ~fp32), writes qk32 + qk16
    k_gemm64<4><<<dim3(H_DIM / 128, B_DIM / 64), 256, 0, stream>>>(
        qnHi, qnLo, wkTh, wkTl, qk32, qk16);

    // row norms of keys: 3-term split GEMM (storeHi+storeLo)@(wkHi+wkLo).T, fused sum-sq epilogue
    k_gemm8<0><<<1024, 512, 0, stream>>>(storeHi, storeLo, wkHi, wkLo, nullptr, nullptr, nrm2);

    // sscale[n] = w[n] / ((sumw+1e-8)*||keys_n||)
    k_fin<<<N_DIM / 256, 256, 0, stream>>>(wbuf, sumw, nrm2, sscale);

    // sim = (qk16 @ storeHi.T) * sscale[col]; fused per-(row, 256-col-chunk) top-8 -> cand
    k_gemm8<1><<<2048, 512, 0, stream>>>(qk16, nullptr, storeHi, nullptr, cand, sscale, nullptr);

    // merge 2048 cands -> top-16, fp32 rescore, top-8+softmax+combine
    k_merge2<<<B_DIM, 256, 0, stream>>>(cand, qk32, sscale, store, s16);

    // (s @ Wv.T) @ Wo.T
    k_gemm64<2><<<dim3(H_DIM / 128, B_DIM / 64), 256, 0, stream>>>(s16, nullptr, wv16, nullptr, nullptr, t16);
    k_gemm64<3><<<dim3(H_DIM / 128, B_DIM / 64), 256, 0, stream>>>(t16, nullptr, wo16, nullptr, out, nullptr);

    (void)in_sizes; (void)n_in; (void)out_size; (void)ws_size;
}

// Round 5
// 1234.415 us; speedup vs baseline: 1.0893x; 1.0893x over previous
//
#include <hip/hip_runtime.h>
#include <stdint.h>

// ---------- types ----------
typedef _Float16 f16;
typedef _Float16 f16x8 __attribute__((ext_vector_type(8)));
typedef _Float16 f16x4 __attribute__((ext_vector_type(4)));
typedef float    f32x4 __attribute__((ext_vector_type(4)));

#define B_DIM 2048
#define N_DIM 65536
#define H_DIM 1024

typedef const __attribute__((address_space(1))) void g_void;
typedef __attribute__((address_space(3))) void l_void;
__device__ __forceinline__ void glds16(const void* g, void* l) {
    __builtin_amdgcn_global_load_lds((g_void*)g, (l_void*)l, 16, 0, 0);
}

// monotone f32 key | 6-bit col
__device__ __forceinline__ unsigned int mkey(float v, unsigned int c6) {
    unsigned int u = __builtin_bit_cast(unsigned int, v);
    u ^= (unsigned int)((int)u >> 31) | 0x80000000u;
    return (u & 0xFFFFFFC0u) | c6;
}

// ---------- small prep kernels ----------
__global__ __launch_bounds__(256) void k_weights(const float* __restrict__ imp,
                                                 const float* __restrict__ ts,
                                                 float* __restrict__ w,
                                                 float* __restrict__ sumw) {
    int i = blockIdx.x * 256 + threadIdx.x;
    float age = 1.0f - ts[i];
    float r = expf(-fabsf(age) * (float)(1.0 - 0.99));
    float wv = r * (imp[i] + 1.0f);
    w[i] = wv;
    for (int off = 32; off; off >>= 1) wv += __shfl_down(wv, off, 64);
    __shared__ float ps[4];
    if ((threadIdx.x & 63) == 0) ps[threadIdx.x >> 6] = wv;
    __syncthreads();
    if (threadIdx.x == 0) atomicAdd(sumw, ps[0] + ps[1] + ps[2] + ps[3]);
}

// split fp32 -> fp16 hi + fp16 lo (8 floats/thread, 16B stores)
__global__ __launch_bounds__(256) void k_split(const float* __restrict__ x,
                                               f16* __restrict__ hi, f16* __restrict__ lo) {
    size_t i = (size_t)blockIdx.x * 256 + threadIdx.x;
    float4 v0 = ((const float4*)x)[2 * i];
    float4 v1 = ((const float4*)x)[2 * i + 1];
    float vv[8] = {v0.x, v0.y, v0.z, v0.w, v1.x, v1.y, v1.z, v1.w};
    f16x8 h, l;
#pragma unroll
    for (int j = 0; j < 8; j++) { h[j] = (f16)vv[j]; l[j] = (f16)(vv[j] - (float)h[j]); }
    ((f16x8*)hi)[i] = h;
    ((f16x8*)lo)[i] = l;
}

__global__ __launch_bounds__(256) void k_tohalf(const float* __restrict__ x, f16* __restrict__ h) {
    size_t i = (size_t)blockIdx.x * 256 + threadIdx.x;
    float4 v0 = ((const float4*)x)[2 * i];
    float4 v1 = ((const float4*)x)[2 * i + 1];
    f16x8 o = {(f16)v0.x, (f16)v0.y, (f16)v0.z, (f16)v0.w,
               (f16)v1.x, (f16)v1.y, (f16)v1.z, (f16)v1.w};
    ((f16x8*)h)[i] = o;
}

// transpose-split: wkT[j,k] = Wk[k,j] -> f16 hi + lo
__global__ __launch_bounds__(256) void k_tsplit(const float* __restrict__ Wm,
                                                f16* __restrict__ th, f16* __restrict__ tl_) {
    __shared__ float tl[64][65];
    const int t = threadIdx.x;
    const int r0 = blockIdx.y * 64, c0 = blockIdx.x * 64;
#pragma unroll
    for (int p = 0; p < 16; ++p) {
        int idx = p * 256 + t;
        int r = idx >> 6, c = idx & 63;
        tl[r][c] = Wm[(size_t)(r0 + r) * H_DIM + c0 + c];
    }
    __syncthreads();
#pragma unroll
    for (int p = 0; p < 16; ++p) {
        int idx = p * 256 + t;
        int oc = idx >> 6, rr = idx & 63;
        float v = tl[rr][oc];
        f16 h = (f16)v;
        th[(size_t)(c0 + oc) * H_DIM + r0 + rr] = h;
        tl_[(size_t)(c0 + oc) * H_DIM + r0 + rr] = (f16)(v - (float)h);
    }
}

// q row-normalize -> fp16 hi + lo
__global__ __launch_bounds__(256) void k_qnorm(const float* __restrict__ q,
                                               f16* __restrict__ qh, f16* __restrict__ ql) {
    int b = blockIdx.x, t = threadIdx.x;
    float4 v = ((const float4*)(q + (size_t)b * H_DIM))[t];
    float ss = v.x * v.x + v.y * v.y + v.z * v.z + v.w * v.w;
    for (int off = 32; off; off >>= 1) ss += __shfl_down(ss, off, 64);
    __shared__ float ps[4];
    if ((t & 63) == 0) ps[t >> 6] = ss;
    __syncthreads();
    float tot = ps[0] + ps[1] + ps[2] + ps[3];
    float rn = 1.0f / fmaxf(sqrtf(tot), 1e-12f);
    float o[4] = {v.x * rn, v.y * rn, v.z * rn, v.w * rn};
    f16x4 h, l;
#pragma unroll
    for (int j = 0; j < 4; j++) { h[j] = (f16)o[j]; l[j] = (f16)(o[j] - (float)h[j]); }
    ((f16x4*)(qh + (size_t)b * H_DIM))[t] = h;
    ((f16x4*)(ql + (size_t)b * H_DIM))[t] = l;
}

// finalize sscale[n] = w[n] / ((sumw+1e-8) * max(sqrt(nrm2[n]),1e-12))
__global__ __launch_bounds__(256) void k_fin(const float* __restrict__ w,
                                             const float* __restrict__ sumw,
                                             const float* __restrict__ nrm2,
                                             float* __restrict__ sscale) {
    int i = blockIdx.x * 256 + threadIdx.x;
    sscale[i] = w[i] / ((sumw[0] + 1e-8f) * fmaxf(sqrtf(nrm2[i]), 1e-12f));
}

// ---------- 8-phase 256x256 GEMM, BK=64, 512 thr (8 waves 2Mx4N), 16x16x32 f16 MFMA ----------
// OUTMODE 0: norm GEMM  C = (storeHi+storeLo) @ (wkHi+wkLo).T (3-term split, virtual K=3072);
//            no C write; epilogue atomicAdd row-wise sum(C^2) -> nrm2
// OUTMODE 1: sim GEMM   C = qk16 @ storeHi.T (K=1024); epilogue: v*colscale, register-only
//            exact per-(row, 64-col slice) top-4 via sorted-quad shfl butterfly -> cand
//
// LDS (128 KiB): A: 2 bufs x [256 rows][64 f16] at 0/32768; B: same at 65536/98304.
//   B rows permuted: lds rows 0-127 = "even" 32-col halves, rows 128-255 = "odd" halves.
//   XOR swizzle: byte slot ^= (lds_row&7)<<4; staged via inverse-swizzled global source.
// Pipeline: tile t+1 staged in 2 groups of 4 glds16; waits vmcnt(4) at phases 0,3 (each
//   retires one 4-load group; loads stay in flight across barriers, never drained).

#define RD_A(AB, H)                                                              \
    _Pragma("unroll") for (int mi = 0; mi < 4; ++mi) {                           \
        a[mi][0] = *(const f16x8*)(lds + (AB) + arow + (H)*8192 + mi*2048 + acol0); \
        a[mi][1] = *(const f16x8*)(lds + (AB) + arow + (H)*8192 + mi*2048 + acol1); \
    }

#define RD_B(DST, BB, OFFH)                                                      \
    _Pragma("unroll") for (int nj = 0; nj < 2; ++nj) {                           \
        DST[nj][0] = *(const f16x8*)(lds + (BB) + (OFFH) + brow + nj*2048 + acol0); \
        DST[nj][1] = *(const f16x8*)(lds + (BB) + (OFFH) + brow + nj*2048 + acol1); \
    }

#define PH_PRE()                                                                 \
    __builtin_amdgcn_s_barrier();                                                \
    asm volatile("s_waitcnt lgkmcnt(0)" ::: "memory");                           \
    __builtin_amdgcn_sched_barrier(0);                                           \
    __builtin_amdgcn_s_setprio(1);

#define PH_POST()                                                                \
    __builtin_amdgcn_s_setprio(0);                                               \
    __builtin_amdgcn_s_barrier();

#define MFMA8x2(MH, BV, NB)                                                      \
    _Pragma("unroll") for (int ks = 0; ks < 2; ++ks)                             \
    _Pragma("unroll") for (int mi = 0; mi < 4; ++mi)                             \
    _Pragma("unroll") for (int nj = 0; nj < 2; ++nj)                             \
        acc[(MH)*4 + mi][(NB) + nj] = __builtin_amdgcn_mfma_f32_16x16x32_f16(    \
            a[mi][ks], BV[nj][ks], acc[(MH)*4 + mi][(NB) + nj], 0, 0, 0);

#define TILE_BODY(T, STG, W0STR)                                                 \
  {                                                                              \
    const int cur = (T) & 1;                                                     \
    const int ab = cur * 32768;                                                  \
    const int bb = 65536 + cur * 32768;                                          \
    const int da = (cur ^ 1) * 32768;                                            \
    const int db = 65536 + (cur ^ 1) * 32768;                                    \
    const f16* An = A0; const f16* Bn = Bh; int toffn = 0;                       \
    if (STG) {                                                                   \
        const int tn = (T) + 1;                                                  \
        if constexpr (OUTMODE == 0) {                                            \
            An = (tn < 16) ? A0 : (tn < 32 ? A1 : A0);                           \
            Bn = (tn < 32) ? Bh : Bl;                                            \
            toffn = (tn & 15) * 64;                                              \
        } else { toffn = tn * 64; }                                              \
    }                                                                            \
    /* phase 0: (m-lo, n-even) */                                                \
    RD_A(ab, 0)                                                                  \
    RD_B(b0, bb, 0)                                                              \
    if (STG) {                                                                   \
        glds16(An + aoff0 + toffn, lds + da + tid * 16);                         \
        glds16(An + aoff2 + toffn, lds + da + 16384 + tid * 16);                 \
        glds16(Bn + boffE1 + toffn, lds + db + tid * 16);                        \
        glds16(Bn + boffE2 + toffn, lds + db + 8192 + tid * 16);                 \
    }                                                                            \
    asm volatile("s_waitcnt vmcnt(" W0STR ")" ::: "memory");                     \
    PH_PRE() MFMA8x2(0, b0, 0) PH_POST()                                         \
    /* phase 1: (m-lo, n-odd) */                                                 \
    RD_B(b1, bb, 16384)                                                          \
    if (STG) {                                                                   \
        glds16(Bn + boffO1 + toffn, lds + db + 16384 + tid * 16);                \
        glds16(Bn + boffO2 + toffn, lds + db + 24576 + tid * 16);                \
        glds16(An + aoff1 + toffn, lds + da + 8192 + tid * 16);                  \
        glds16(An + aoff3 + toffn, lds + da + 24576 + tid * 16);                 \
    }                                                                            \
    PH_PRE() MFMA8x2(0, b1, 2) PH_POST()                                         \
    /* phase 2: (m-hi, n-odd) */                                                 \
    RD_A(ab, 1)                                                                  \
    PH_PRE() MFMA8x2(1, b1, 2) PH_POST()                                         \
    /* phase 3: (m-hi, n-even) */                                                \
    asm volatile("s_waitcnt vmcnt(4)" ::: "memory");                             \
    PH_PRE() MFMA8x2(1, b0, 0) PH_POST()                                         \
  }

#define CMPSWAP(x, y) { unsigned int hi_ = max(x, y), lo_ = min(x, y); x = hi_; y = lo_; }

template <int OUTMODE>
__global__ __launch_bounds__(512) void k_gemm8(
    const f16* __restrict__ A0, const f16* __restrict__ A1,
    const f16* __restrict__ Bh, const f16* __restrict__ Bl,
    unsigned int* __restrict__ cand, const float* __restrict__ colscale,
    float* __restrict__ nrm2) {
    __shared__ char lds[131072];
    const int tid = threadIdx.x;

    constexpr int NT = (OUTMODE == 0) ? 48 : 16;  // virtual K = 3072 (split) vs 1024

    // XCD-chunked bijective block swizzle
    int m0, n0;
    {
        const int f = blockIdx.x;
        if constexpr (OUTMODE == 0) {
            // 1024 blocks = 256 M-tiles x 4 N-tiles, N fastest within an XCD chunk of 128
            const int lg = (f & 7) * 128 + (f >> 3);
            m0 = (lg >> 2) * 256; n0 = (lg & 3) * 256;
        } else {
            // 2048 blocks = 8 M-tiles x 256 N-tiles, M fastest within an XCD chunk of 256
            const int lg = (f & 7) * 256 + (f >> 3);
            m0 = (lg & 7) * 256; n0 = (lg >> 3) * 256;
        }
    }

    // staging coords: thread -> (row-in-chunk, 16B slot); global source pre-inverse-swizzled
    const int sr = tid >> 3, ss = tid & 7;
    const int ssw = (ss ^ (sr & 7)) * 8;  // element offset
    const size_t aoff0 = (size_t)(m0 + sr) * H_DIM + ssw;
    const size_t aoff1 = (size_t)(m0 + 64 + sr) * H_DIM + ssw;
    const size_t aoff2 = (size_t)(m0 + 128 + sr) * H_DIM + ssw;
    const size_t aoff3 = (size_t)(m0 + 192 + sr) * H_DIM + ssw;
    const int nE = (sr >> 5) * 64 + (sr & 31);
    const size_t boffE1 = (size_t)(n0 + nE) * H_DIM + ssw;
    const size_t boffE2 = (size_t)(n0 + nE + 128) * H_DIM + ssw;
    const size_t boffO1 = (size_t)(n0 + nE + 32) * H_DIM + ssw;
    const size_t boffO2 = (size_t)(n0 + nE + 160) * H_DIM + ssw;

    // reader coords
    const int lane = tid & 63, wave = tid >> 6;
    const int wr = wave >> 2, wc = wave & 3;
    const int m16 = lane & 15, q4 = lane >> 4;
    const int axor = (lane & 7) << 4;
    const int acol0 = (q4 * 16) ^ axor;
    const int acol1 = (64 + q4 * 16) ^ axor;
    const int arow = (wr * 128 + m16) * 128;
    const int brow = (wc * 32 + m16) * 128;

    f32x4 acc[8][4];
#pragma unroll
    for (int i = 0; i < 8; i++)
#pragma unroll
        for (int j = 0; j < 4; j++) acc[i][j] = (f32x4){0.f, 0.f, 0.f, 0.f};
    f16x8 a[4][2], b0[2][2], b1[2][2];

    // prologue: stage tile 0 into buf0 (group1 then group2), wait group1, barrier
    glds16(A0 + aoff0, lds + tid * 16);
    glds16(A0 + aoff2, lds + 16384 + tid * 16);
    glds16(Bh + boffE1, lds + 65536 + tid * 16);
    glds16(Bh + boffE2, lds + 65536 + 8192 + tid * 16);
    glds16(Bh + boffO1, lds + 65536 + 16384 + tid * 16);
    glds16(Bh + boffO2, lds + 65536 + 24576 + tid * 16);
    glds16(A0 + aoff1, lds + 8192 + tid * 16);
    glds16(A0 + aoff3, lds + 24576 + tid * 16);
    asm volatile("s_waitcnt vmcnt(4)" ::: "memory");
    __builtin_amdgcn_s_barrier();

    for (int t = 0; t < NT - 1; ++t) TILE_BODY(t, 1, "4")
    TILE_BODY(NT - 1, 0, "0")

    if constexpr (OUTMODE == 0) {
        // row-wise sum of squares over this block's 256 cols -> atomicAdd into nrm2
#pragma unroll
        for (int mi = 0; mi < 8; ++mi)
#pragma unroll
            for (int rr = 0; rr < 4; ++rr) {
                float s = 0.f;
#pragma unroll
                for (int njj = 0; njj < 4; ++njj) {
                    float v = acc[mi][njj][rr];
                    s += v * v;
                }
                s += __shfl_xor(s, 1, 64);
                s += __shfl_xor(s, 2, 64);
                s += __shfl_xor(s, 4, 64);
                s += __shfl_xor(s, 8, 64);
                if (m16 == 0)
                    atomicAdd(&nrm2[m0 + wr * 128 + mi * 16 + q4 * 4 + rr], s);
            }
    } else {
        // exact per-(row, 64-col slice) top-4, register-only
        float cs0 = colscale[n0 + wc * 64 + m16];
        float cs1 = colscale[n0 + wc * 64 + 16 + m16];
        float cs2 = colscale[n0 + wc * 64 + 32 + m16];
        float cs3 = colscale[n0 + wc * 64 + 48 + m16];
        const unsigned int c6_0 = (unsigned)m16;            // njj0 -> col 0..15
        const unsigned int c6_1 = (unsigned)(16 + m16);     // njj1 -> col 16..31
        const unsigned int c6_2 = (unsigned)(32 + m16);     // njj2 -> col 32..47
        const unsigned int c6_3 = (unsigned)(48 + m16);     // njj3 -> col 48..63
        const int slice = (n0 >> 6) + wc;

#pragma unroll
        for (int mi = 0; mi < 8; ++mi)
#pragma unroll
            for (int rr = 0; rr < 4; ++rr) {
                unsigned int k0 = mkey(acc[mi][0][rr] * cs0, c6_0);
                unsigned int k1 = mkey(acc[mi][1][rr] * cs1, c6_1);
                unsigned int k2 = mkey(acc[mi][2][rr] * cs2, c6_2);
                unsigned int k3 = mkey(acc[mi][3][rr] * cs3, c6_3);
                // sort descending: 5-comparator network
                CMPSWAP(k0, k1) CMPSWAP(k2, k3) CMPSWAP(k0, k2) CMPSWAP(k1, k3) CMPSWAP(k1, k2)
                // butterfly over the 16 m16-lanes, merging sorted quads exactly
#pragma unroll
                for (int mm = 1; mm <= 8; mm <<= 1) {
                    unsigned int p0 = __shfl_xor(k0, mm, 64);
                    unsigned int p1 = __shfl_xor(k1, mm, 64);
                    unsigned int p2 = __shfl_xor(k2, mm, 64);
                    unsigned int p3 = __shfl_xor(k3, mm, 64);
                    unsigned int L0 = max(k0, p0), H0 = min(k0, p0);
                    unsigned int L1 = max(k1, p1), H1 = min(k1, p1);
                    unsigned int L2 = max(k2, p2);
                    unsigned int L3 = max(k3, p3);
                    unsigned int r1 = max(H0, L1);
                    unsigned int m_ = min(H0, L1);
                    unsigned int r2 = max(m_, max(H1, L2));
                    unsigned int md = max(min(m_, H1), min(max(m_, H1), L2));  // med3
                    unsigned int r3 = max(md, L3);
                    k0 = L0; k1 = r1; k2 = r2; k3 = r3;
                }
                if (m16 == 0) {
                    const int b = m0 + wr * 128 + mi * 16 + q4 * 4 + rr;
                    *(uint4*)(cand + (size_t)b * 4096 + slice * 4) = (uint4){k0, k1, k2, k3};
                }
            }
    }
    (void)A1; (void)Bl; (void)nrm2; (void)colscale; (void)cand;
}

// ---------- small GEMM: C[2048,1024] = A[2048,1024] * B[1024,1024]^T ; 64x128 tile ----------
// OUTMODE 2: fp16 out; OUTMODE 3: fp32 out; OUTMODE 4: 3-term fp16-split (A=Ah+Al, B=Bh+Bl), fp32+fp16 out
template <int OUTMODE>
__global__ __launch_bounds__(256) void k_gemm64(const f16* __restrict__ A, const f16* __restrict__ Al,
                                                const f16* __restrict__ B, const f16* __restrict__ Bl,
                                                float* __restrict__ of32, f16* __restrict__ of16) {
    __shared__ f16 As[64 * 32];
    __shared__ f16 Bs[128 * 32];
    __shared__ f16 AsL[(OUTMODE == 4) ? 64 * 32 : 1];
    __shared__ f16 BsL[(OUTMODE == 4) ? 128 * 32 : 1];
    const int tid = threadIdx.x;
    const int m0 = blockIdx.y * 64, n0 = blockIdx.x * 128;
    const int r = tid >> 2, c8 = (tid & 3) * 8;
    const f16* ga = A + (size_t)(m0 + r) * H_DIM + c8;
    const f16* gb0 = B + (size_t)(n0 + r) * H_DIM + c8;
    const f16* gb1 = B + (size_t)(n0 + r + 64) * H_DIM + c8;
    const f16 *gal = nullptr, *gbl0 = nullptr, *gbl1 = nullptr;
    if constexpr (OUTMODE == 4) {
        gal = Al + (size_t)(m0 + r) * H_DIM + c8;
        gbl0 = Bl + (size_t)(n0 + r) * H_DIM + c8;
        gbl1 = Bl + (size_t)(n0 + r + 64) * H_DIM + c8;
    }

    const int lane = tid & 63, wave = tid >> 6;
    const int wn = wave * 32;
    const int q4 = lane >> 4, m16 = lane & 15;
    const int aoff = m16 * 32 + q4 * 8;
    const int boff = (wn + m16) * 32 + q4 * 8;

    f32x4 acc[4][2];
#pragma unroll
    for (int i = 0; i < 4; i++)
#pragma unroll
        for (int j = 0; j < 2; j++) acc[i][j] = (f32x4){0.f, 0.f, 0.f, 0.f};

    for (int k0 = 0; k0 < H_DIM; k0 += 32) {
        __syncthreads();
        glds16(ga + k0, As + tid * 8);
        glds16(gb0 + k0, Bs + tid * 8);
        glds16(gb1 + k0, Bs + 2048 + tid * 8);
        if constexpr (OUTMODE == 4) {
            glds16(gal + k0, AsL + tid * 8);
            glds16(gbl0 + k0, BsL + tid * 8);
            glds16(gbl1 + k0, BsL + 2048 + tid * 8);
        }
        __syncthreads();
        f16x8 a[4], b[2], al[4], bl[2];
#pragma unroll
        for (int i = 0; i < 4; i++) a[i] = *(const f16x8*)(As + aoff + i * 512);
#pragma unroll
        for (int j = 0; j < 2; j++) b[j] = *(const f16x8*)(Bs + boff + j * 512);
        if constexpr (OUTMODE == 4) {
#pragma unroll
            for (int i = 0; i < 4; i++) al[i] = *(const f16x8*)(AsL + aoff + i * 512);
#pragma unroll
            for (int j = 0; j < 2; j++) bl[j] = *(const f16x8*)(BsL + boff + j * 512);
        }
#pragma unroll
        for (int i = 0; i < 4; i++)
#pragma unroll
            for (int j = 0; j < 2; j++) {
                if constexpr (OUTMODE == 4) {
                    acc[i][j] = __builtin_amdgcn_mfma_f32_16x16x32_f16(al[i], b[j], acc[i][j], 0, 0, 0);
                    acc[i][j] = __builtin_amdgcn_mfma_f32_16x16x32_f16(a[i], bl[j], acc[i][j], 0, 0, 0);
                }
                acc[i][j] = __builtin_amdgcn_mfma_f32_16x16x32_f16(a[i], b[j], acc[i][j], 0, 0, 0);
            }
    }

#pragma unroll
    for (int i = 0; i < 4; i++) {
        const int rowb = m0 + i * 16 + q4 * 4;
#pragma unroll
        for (int j = 0; j < 2; j++) {
            const int col = n0 + wn + j * 16 + m16;
#pragma unroll
            for (int rr = 0; rr < 4; rr++) {
                const float v = acc[i][j][rr];
                const size_t o = (size_t)(rowb + rr) * H_DIM + col;
                if constexpr (OUTMODE == 2) of16[o] = (f16)v;
                else if constexpr (OUTMODE == 3) of32[o] = v;
                else { of32[o] = v; of16[o] = (f16)v; }
            }
        }
    }
}

// ---------- merge 4096 packed cands -> top-16; fp32 rescore; top-8 + softmax; combine ----------
__global__ __launch_bounds__(256) void k_merge2(const unsigned int* __restrict__ cand,
                                                const float* __restrict__ qk32,
                                                const float* __restrict__ sscale,
                                                const float* __restrict__ store,
                                                f16* __restrict__ s16) {
    const int b = blockIdx.x, t = threadIdx.x;
    __shared__ unsigned int cl[4096];
    __shared__ unsigned int wmax[2][4];
    __shared__ int c16[16];
    __shared__ float rs[16];
    __shared__ float a8[8];
    __shared__ int i8[8];

    const uint4* src = (const uint4*)(cand + (size_t)b * 4096);
    uint4 e0 = src[t * 4];
    uint4 e1 = src[t * 4 + 1];
    uint4 e2 = src[t * 4 + 2];
    uint4 e3 = src[t * 4 + 3];
    ((uint4*)cl)[t * 4] = e0;
    ((uint4*)cl)[t * 4 + 1] = e1;
    ((uint4*)cl)[t * 4 + 2] = e2;
    ((uint4*)cl)[t * 4 + 3] = e3;
    unsigned int k_[16] = {e0.x, e0.y, e0.z, e0.w, e1.x, e1.y, e1.z, e1.w,
                           e2.x, e2.y, e2.z, e2.w, e3.x, e3.y, e3.z, e3.w};
#pragma unroll
    for (int i = 0; i < 16; ++i) k_[i] = (k_[i] & 0xFFFFF000u) | (unsigned)(t * 16 + i);
    __syncthreads();

    const int w = t >> 6;
    for (int rnd = 0; rnd < 16; ++rnd) {
        unsigned int lm = k_[0];
#pragma unroll
        for (int i = 1; i < 16; ++i) lm = max(lm, k_[i]);
        for (int off = 32; off; off >>= 1) lm = max(lm, __shfl_down(lm, off, 64));
        if ((t & 63) == 0) wmax[rnd & 1][w] = lm;
        __syncthreads();
        unsigned int win = max(max(wmax[rnd & 1][0], wmax[rnd & 1][1]),
                               max(wmax[rnd & 1][2], wmax[rnd & 1][3]));
        int slot = (int)(win & 0xFFFu);
        if (t == 0) c16[rnd] = (slot >> 2) * 64 + (int)(cl[slot] & 63u);
        const bool own = (slot >> 4) == t;
#pragma unroll
        for (int i = 0; i < 16; ++i) k_[i] = (own && i == (slot & 15)) ? 0u : k_[i];
    }
    __syncthreads();

    // fp32 rescore: group g (16 lanes) handles candidate g; score = qk32[b] . store[idx] * sscale[idx]
    const int g = t >> 4, l16 = t & 15;
    const int idx = c16[g];
    const float* kr = store + (size_t)idx * H_DIM;
    const float* qr = qk32 + (size_t)b * H_DIM;
    float sum = 0.f;
#pragma unroll 8
    for (int j = 0; j < 64; j++) {
        int k = l16 + j * 16;
        sum += qr[k] * kr[k];
    }
    for (int off = 8; off; off >>= 1) sum += __shfl_down(sum, off, 16);
    if (l16 == 0) rs[g] = sum * sscale[idx];
    __syncthreads();

    if (t == 0) {
        float v[16];
        for (int i = 0; i < 16; i++) v[i] = rs[i];
        float av[8]; int ai[8];
        for (int it = 0; it < 8; ++it) {
            float bm = -1e30f; int mi = 0;
            for (int i = 0; i < 16; i++)
                if (v[i] > bm) { bm = v[i]; mi = i; }
            av[it] = bm; ai[it] = c16[mi]; v[mi] = -1e30f;
        }
        float m = av[0], e[8], ssum = 0.f;
        for (int k = 0; k < 8; k++) { e[k] = expf(av[k] - m); ssum += e[k]; }
        for (int k = 0; k < 8; k++) { a8[k] = e[k] / ssum; i8[k] = ai[k]; }
    }
    __syncthreads();

#pragma unroll
    for (int p = 0; p < 4; p++) {
        const int col = t + p * 256;
        float sum2 = 0.f;
#pragma unroll
        for (int k = 0; k < 8; k++) sum2 += a8[k] * store[(size_t)i8[k] * H_DIM + col];
        s16[(size_t)b * H_DIM + col] = (f16)sum2;
    }
}

// ---------- workspace layout (bytes) ----------
#define MB (1024ull * 1024ull)
#define OFF_STOREHI (0ull)               // 128 MB
#define OFF_STORELO (128ull * MB)        // 128 MB
#define OFF_CAND    (256ull * MB)        // 32 MB (top-4 per (query, 64-col slice))
#define OFF_WKHI    (512ull * MB)        // 2 MB
#define OFF_WKLO    (514ull * MB)        // 2 MB
#define OFF_WKTH    (516ull * MB)        // 2 MB
#define OFF_WKTL    (518ull * MB)        // 2 MB
#define OFF_QNHI    (520ull * MB)        // 4 MB
#define OFF_QNLO    (524ull * MB)        // 4 MB
#define OFF_QK32    (528ull * MB)        // 8 MB
#define OFF_QK16    (536ull * MB)        // 4 MB
#define OFF_WV16    (540ull * MB)        // 2 MB
#define OFF_WO16    (542ull * MB)        // 2 MB
#define OFF_W       (544ull * MB)        // 256 KB
#define OFF_SSCALE  (544ull * MB + 256ull * 1024ull)
#define OFF_SUMW    (544ull * MB + 512ull * 1024ull)
#define OFF_NRM2    (544ull * MB + 768ull * 1024ull)  // 256 KB
#define OFF_S16     (546ull * MB)        // 4 MB
#define OFF_T16     (550ull * MB)        // 4 MB

extern "C" void kernel_launch(void* const* d_in, const int* in_sizes, int n_in,
                              void* d_out, int out_size, void* d_ws, size_t ws_size,
                              hipStream_t stream) {
    const float* q     = (const float*)d_in[0];
    const float* store = (const float*)d_in[1];
    const float* imp   = (const float*)d_in[2];
    const float* ts    = (const float*)d_in[3];
    const float* Wk    = (const float*)d_in[4];
    const float* Wv    = (const float*)d_in[5];
    const float* Wo    = (const float*)d_in[6];
    float* out = (float*)d_out;
    char* ws = (char*)d_ws;

    f16* storeHi = (f16*)(ws + OFF_STOREHI);
    f16* storeLo = (f16*)(ws + OFF_STORELO);
    unsigned int* cand = (unsigned int*)(ws + OFF_CAND);
    f16* wkHi = (f16*)(ws + OFF_WKHI);
    f16* wkLo = (f16*)(ws + OFF_WKLO);
    f16* wkTh = (f16*)(ws + OFF_WKTH);
    f16* wkTl = (f16*)(ws + OFF_WKTL);
    f16* qnHi = (f16*)(ws + OFF_QNHI);
    f16* qnLo = (f16*)(ws + OFF_QNLO);
    float* qk32 = (float*)(ws + OFF_QK32);
    f16* qk16 = (f16*)(ws + OFF_QK16);
    f16* wv16 = (f16*)(ws + OFF_WV16);
    f16* wo16 = (f16*)(ws + OFF_WO16);
    float* wbuf = (float*)(ws + OFF_W);
    float* sscale = (float*)(ws + OFF_SSCALE);
    float* sumw = (float*)(ws + OFF_SUMW);
    float* nrm2 = (float*)(ws + OFF_NRM2);
    f16* s16 = (f16*)(ws + OFF_S16);
    f16* t16 = (f16*)(ws + OFF_T16);

    hipMemsetAsync(sumw, 0, 4, stream);
    hipMemsetAsync(nrm2, 0, N_DIM * 4, stream);

    // prep
    k_weights<<<N_DIM / 256, 256, 0, stream>>>(imp, ts, wbuf, sumw);
    k_split<<<(N_DIM * H_DIM) / 2048, 256, 0, stream>>>(store, storeHi, storeLo);
    k_split<<<(H_DIM * H_DIM) / 2048, 256, 0, stream>>>(Wk, wkHi, wkLo);
    k_tsplit<<<dim3(16, 16), 256, 0, stream>>>(Wk, wkTh, wkTl);
    k_tohalf<<<(H_DIM * H_DIM) / 2048, 256, 0, stream>>>(Wv, wv16);
    k_tohalf<<<(H_DIM * H_DIM) / 2048, 256, 0, stream>>>(Wo, wo16);
    k_qnorm<<<B_DIM, 256, 0, stream>>>(q, qnHi, qnLo);

    // qk = qn @ Wk (3-term fp16 split -> ~fp32), writes qk32 + qk16
    k_gemm64<4><<<dim3(H_DIM / 128, B_DIM / 64), 256, 0, stream>>>(
        qnHi, qnLo, wkTh, wkTl, qk32, qk16);

    // row norms of keys: 3-term split GEMM (storeHi+storeLo)@(wkHi+wkLo).T, fused sum-sq epilogue
    k_gemm8<0><<<1024, 512, 0, stream>>>(storeHi, storeLo, wkHi, wkLo, nullptr, nullptr, nrm2);

    // sscale[n] = w[n] / ((sumw+1e-8)*||keys_n||)
    k_fin<<<N_DIM / 256, 256, 0, stream>>>(wbuf, sumw, nrm2, sscale);

    // sim = (qk16 @ storeHi.T) * sscale[col]; fused register-only per-(row, 64-col) top-4 -> cand
    k_gemm8<1><<<2048, 512, 0, stream>>>(qk16, nullptr, storeHi, nullptr, cand, sscale, nullptr);

    // merge 4096 cands -> top-16, fp32 rescore, top-8+softmax+combine
    k_merge2<<<B_DIM, 256, 0, stream>>>(cand, qk32, sscale, store, s16);

    // (s @ Wv.T) @ Wo.T
    k_gemm64<2><<<dim3(H_DIM / 128, B_DIM / 64), 256, 0, stream>>>(s16, nullptr, wv16, nullptr, nullptr, t16);
    k_gemm64<3><<<dim3(H_DIM / 128, B_DIM / 64), 256, 0, stream>>>(t16, nullptr, wo16, nullptr, out, nullptr);

    (void)in_sizes; (void)n_in; (void)out_size; (void)ws_size;
}